// Round 1
// baseline (296.601 us; speedup 1.0000x reference)
//
#include <hip/hip_runtime.h>

#define TWO_M 512
#define NCOL  64

// ---------------- Kernel A: per-batch Gram (64x64) + scalar recurrence ----------------
// grid = B, block = 256 (4 waves). Emits cf[batch*128 + l] = b_l, cf[batch*128+64+l] = 1/d_l.
__global__ __launch_bounds__(256) void gs_gram_rec(const float* __restrict__ y,
                                                   float* __restrict__ cf)
{
    __shared__ float Ych[64 * 64];   // 16 KB chunk of Y (64 rows x 64 cols)
    __shared__ float Gl[64 * 64];    // 16 KB Gram matrix

    const int batch = blockIdx.x;
    const float* Y = y + (size_t)batch * (TWO_M * NCOL);
    const int tid  = threadIdx.x;
    const int wave = tid >> 6;
    const int lane = tid & 63;
    const int ca = (lane & 7) << 3;   // G col block (8 cols)
    const int cb = (lane >> 3) << 3;  // G row block (8 rows)

    float acc[8][8];
#pragma unroll
    for (int p = 0; p < 8; ++p)
#pragma unroll
        for (int q = 0; q < 8; ++q) acc[p][q] = 0.f;

    // 8 chunks of 64 rows; each wave takes 16 rows of each chunk (k-split)
    for (int c = 0; c < 8; ++c) {
        __syncthreads();
        const float4* src = (const float4*)(Y + c * 64 * NCOL);
        float4* dst = (float4*)Ych;
#pragma unroll
        for (int t = 0; t < 4; ++t) dst[tid + t * 256] = src[tid + t * 256];
        __syncthreads();
#pragma unroll
        for (int kk = 0; kk < 16; ++kk) {
            const float4* row4 = (const float4*)(Ych + (wave * 16 + kk) * 64);
            float4 a0 = row4[(ca >> 2) + 0];
            float4 a1 = row4[(ca >> 2) + 1];
            float4 b0 = row4[(cb >> 2) + 0];
            float4 b1 = row4[(cb >> 2) + 1];
            float av[8] = {a0.x, a0.y, a0.z, a0.w, a1.x, a1.y, a1.z, a1.w};
            float bv[8] = {b0.x, b0.y, b0.z, b0.w, b1.x, b1.y, b1.z, b1.w};
#pragma unroll
            for (int p = 0; p < 8; ++p)
#pragma unroll
                for (int q = 0; q < 8; ++q)
                    acc[p][q] = fmaf(bv[p], av[q], acc[p][q]);
        }
    }

    // cross-wave reduction of partial Gram into Gl (barrier-sequenced adds)
    for (int w = 0; w < 4; ++w) {
        if (wave == w) {
#pragma unroll
            for (int p = 0; p < 8; ++p) {
                float* g = Gl + (cb + p) * 64 + ca;
                if (w == 0) {
#pragma unroll
                    for (int q = 0; q < 8; ++q) g[q] = acc[p][q];
                } else {
#pragma unroll
                    for (int q = 0; q < 8; ++q) g[q] += acc[p][q];
                }
            }
        }
        __syncthreads();
    }

    if (wave != 0) return;   // recurrence on wave 0 only

    const int l = lane;
    const float d     = Gl[l * 64 + l];
    const float invd  = 1.0f / d;
    const float invd0 = __shfl(invd, 0);
    // j = 0 step:  T_{l,0} = G_{l,0}/d_0  (G symmetric -> read row 0 contiguous)
    float T  = Gl[l] * invd0;
    float r  = T;
    float Nq = __shfl(T, 0) * invd0;   // N_0 = ||Q_0||^2
    float bj = __shfl(r, 1);           // b_1
    float bsave = 0.f;                 // b_0 = 0 (unused)

    for (int j = 1; j < 64; ++j) {
        const float invdj = __shfl(invd, j);
        const float Tprev = T;
        T = (Gl[j * 64 + l] - bj * Tprev) * invdj;          // T_{l,j}
        const float cj = (__shfl(Tprev, j) - bj * Nq) * invdj;  // <Q_{j-1},Q_j>
        Nq = (__shfl(T, j) - bj * cj) * invdj;              // ||Q_j||^2
        r  = T - r * cj;                                    // r^{(l)}_j
        if (l == j) bsave = bj;                             // save b_j
        bj = __shfl(r, (j + 1) & 63);                       // b_{j+1}
    }

    float* outc = cf + (size_t)batch * 128;
    outc[l]      = bsave;
    outc[64 + l] = invd;
}

// ---------------- Kernel B: row-parallel output recurrence ----------------
// Q[r,i] = (y[r,i] - b_i * Q[r,i-1]) * invd_i ; one thread per row.
__global__ __launch_bounds__(256) void gs_apply(const float* __restrict__ y,
                                                const float* __restrict__ cf,
                                                float* __restrict__ out)
{
    __shared__ float bd[128];
    const int batch = blockIdx.x >> 1;
    const int half  = blockIdx.x & 1;
    const int tid   = threadIdx.x;
    if (tid < 128) bd[tid] = cf[(size_t)batch * 128 + tid];
    __syncthreads();

    const size_t rowbase = (size_t)batch * (TWO_M * NCOL) + (size_t)(half * 256 + tid) * NCOL;
    const float4* src = (const float4*)(y + rowbase);
    float4 v[16];
#pragma unroll
    for (int t = 0; t < 16; ++t) v[t] = src[t];
    float* vf = (float*)v;
    float q = 0.f;
#pragma unroll
    for (int i = 0; i < 64; ++i) {
        q = (vf[i] - bd[i] * q) * bd[64 + i];
        vf[i] = q;
    }
    float4* dst = (float4*)(out + rowbase);
#pragma unroll
    for (int t = 0; t < 16; ++t) dst[t] = v[t];
}

extern "C" void kernel_launch(void* const* d_in, const int* in_sizes, int n_in,
                              void* d_out, int out_size, void* d_ws, size_t ws_size,
                              hipStream_t stream)
{
    const float* y = (const float*)d_in[0];
    float* out = (float*)d_out;
    float* cf  = (float*)d_ws;           // B * 128 floats = 1 MB
    const int B = in_sizes[0] / (TWO_M * NCOL);
    gs_gram_rec<<<dim3(B), dim3(256), 0, stream>>>(y, cf);
    gs_apply<<<dim3(B * 2), dim3(256), 0, stream>>>(y, cf, out);
}

// Round 2
// 167.375 us; speedup vs baseline: 1.7721x; 1.7721x over previous
//
#include <hip/hip_runtime.h>

#define TWO_M 512
#define NCOL  64
#define S_YT  136   // bf16 elements per Yt row (128 + 8 pad, keeps 16B alignment)

typedef short  short8 __attribute__((ext_vector_type(8)));
typedef float  f32x4  __attribute__((ext_vector_type(4)));

static __device__ __forceinline__ unsigned short f2bf(float f) {
    unsigned int u = __builtin_bit_cast(unsigned int, f);
    unsigned int r = (u + 0x7fffu + ((u >> 16) & 1u)) >> 16;   // RNE
    return (unsigned short)r;
}

// ---------------- Kernel A: per-batch Gram via bf16 MFMA + scalar recurrence ----------------
// grid = B, block = 256 (4 waves). Emits cf[batch*128 + l] = b_l, cf[batch*128+64+l] = 1/d_l.
__global__ __launch_bounds__(256) void gs_gram_mfma(const float* __restrict__ y,
                                                    float* __restrict__ cf)
{
    __shared__ __align__(16) unsigned short Yt[64 * S_YT];  // [col][k] bf16, 17408 B
    __shared__ float Gl[64 * 64];                            // 16 KB

    const int batch = blockIdx.x;
    const float* Y = y + (size_t)batch * (TWO_M * NCOL);
    const int tid  = threadIdx.x;
    const int wave = tid >> 6;
    const int lane = tid & 63;

    f32x4 acc[4] = {f32x4{0,0,0,0}, f32x4{0,0,0,0}, f32x4{0,0,0,0}, f32x4{0,0,0,0}};

    unsigned int* Yt32 = (unsigned int*)Yt;
    const int arow = 16 * wave + (lane & 15);     // A-fragment row (wave's G-row slab)
    const int koff = (lane >> 4) * 8;             // k sub-offset within fragment

    for (int c = 0; c < 4; ++c) {
        const int kbase = c * 128;
        __syncthreads();   // Yt free to overwrite
        // ---- stage 128 k-rows, transposed+converted to bf16 ----
#pragma unroll
        for (int it = 0; it < 4; ++it) {
            const int g  = it * 256 + tid;      // 0..1023 pair index
            const int kp = g >> 4;              // local k-pair 0..63
            const int cq = g & 15;              // float4 column index
            const float4* src = (const float4*)(Y + (size_t)(kbase + 2 * kp) * NCOL);
            const float4 va = src[cq];
            const float4 vb = src[16 + cq];     // row k+1
            const unsigned int p0 = (unsigned int)f2bf(va.x) | ((unsigned int)f2bf(vb.x) << 16);
            const unsigned int p1 = (unsigned int)f2bf(va.y) | ((unsigned int)f2bf(vb.y) << 16);
            const unsigned int p2 = (unsigned int)f2bf(va.z) | ((unsigned int)f2bf(vb.z) << 16);
            const unsigned int p3 = (unsigned int)f2bf(va.w) | ((unsigned int)f2bf(vb.w) << 16);
            const int c0 = 4 * cq;
            Yt32[(c0 + 0) * (S_YT / 2) + kp] = p0;
            Yt32[(c0 + 1) * (S_YT / 2) + kp] = p1;
            Yt32[(c0 + 2) * (S_YT / 2) + kp] = p2;
            Yt32[(c0 + 3) * (S_YT / 2) + kp] = p3;
        }
        __syncthreads();
        // ---- MFMA: wave w computes G rows 16w..16w+15, all 64 cols ----
#pragma unroll
        for (int kb = 0; kb < 128; kb += 32) {
            const short8 afrag = *(const short8*)&Yt[arow * S_YT + kb + koff];
#pragma unroll
            for (int j = 0; j < 4; ++j) {
                const short8 bfrag = *(const short8*)&Yt[(16 * j + (lane & 15)) * S_YT + kb + koff];
                acc[j] = __builtin_amdgcn_mfma_f32_16x16x32_bf16(afrag, bfrag, acc[j], 0, 0, 0);
            }
        }
    }

    // ---- write G slab (disjoint per wave) ----
#pragma unroll
    for (int j = 0; j < 4; ++j)
#pragma unroll
        for (int reg = 0; reg < 4; ++reg) {
            const int gr = 16 * wave + (lane >> 4) * 4 + reg;   // C/D row
            const int gc = 16 * j + (lane & 15);                // C/D col
            Gl[gr * 64 + gc] = acc[j][reg];
        }
    __syncthreads();

    if (wave != 0) return;   // recurrence on wave 0 only (identical to verified R1 code)

    const int l = lane;
    const float d     = Gl[l * 64 + l];
    const float invd  = 1.0f / d;
    const float invd0 = __shfl(invd, 0);
    float T  = Gl[l] * invd0;
    float r  = T;
    float Nq = __shfl(T, 0) * invd0;
    float bj = __shfl(r, 1);
    float bsave = 0.f;

    for (int j = 1; j < 64; ++j) {
        const float invdj = __shfl(invd, j);
        const float Tprev = T;
        T = (Gl[j * 64 + l] - bj * Tprev) * invdj;
        const float cj = (__shfl(Tprev, j) - bj * Nq) * invdj;
        Nq = (__shfl(T, j) - bj * cj) * invdj;
        r  = T - r * cj;
        if (l == j) bsave = bj;
        bj = __shfl(r, (j + 1) & 63);
    }

    float* outc = cf + (size_t)batch * 128;
    outc[l]      = bsave;
    outc[64 + l] = invd;
}

// ---------------- Kernel B: LDS-transposed output recurrence (coalesced I/O) ----------------
// grid = 2B, block = 256. Each block: 256 rows staged through LDS tile [256][65].
__global__ __launch_bounds__(256) void gs_apply2(const float* __restrict__ y,
                                                 const float* __restrict__ cf,
                                                 float* __restrict__ out)
{
    __shared__ float T[256 * 65];   // 66560 B, odd stride -> conflict-free patterns
    __shared__ float bd[128];

    const int tid   = threadIdx.x;
    const int batch = blockIdx.x >> 1;
    const int half  = blockIdx.x & 1;
    if (tid < 128) bd[tid] = cf[(size_t)batch * 128 + tid];

    const size_t tilebase = (size_t)batch * (TWO_M * NCOL) + (size_t)half * 256 * NCOL;
    const float4* src = (const float4*)(y + tilebase);

    // coalesced load -> LDS (scalar writes, banks spread by stride 65)
#pragma unroll
    for (int it = 0; it < 16; ++it) {
        const int g   = it * 256 + tid;
        const int row = g >> 4;
        const int cq  = g & 15;
        const float4 v = src[g];
        float* d = &T[row * 65 + cq * 4];
        d[0] = v.x; d[1] = v.y; d[2] = v.z; d[3] = v.w;
    }
    __syncthreads();

    // per-thread row recurrence: Q[i] = (y[i] - b_i*Q[i-1]) * invd_i
    {
        float q = 0.f;
        float* r = &T[tid * 65];
#pragma unroll
        for (int i = 0; i < 64; ++i) {
            q = (r[i] - bd[i] * q) * bd[64 + i];
            r[i] = q;
        }
    }
    __syncthreads();

    // coalesced store
    float4* dst = (float4*)(out + tilebase);
#pragma unroll
    for (int it = 0; it < 16; ++it) {
        const int g   = it * 256 + tid;
        const int row = g >> 4;
        const int cq  = g & 15;
        const float* s = &T[row * 65 + cq * 4];
        dst[g] = float4{s[0], s[1], s[2], s[3]};
    }
}

extern "C" void kernel_launch(void* const* d_in, const int* in_sizes, int n_in,
                              void* d_out, int out_size, void* d_ws, size_t ws_size,
                              hipStream_t stream)
{
    const float* y = (const float*)d_in[0];
    float* out = (float*)d_out;
    float* cf  = (float*)d_ws;           // B * 128 floats = 1 MB
    const int B = in_sizes[0] / (TWO_M * NCOL);
    gs_gram_mfma<<<dim3(B), dim3(256), 0, stream>>>(y, cf);
    gs_apply2<<<dim3(B * 2), dim3(256), 0, stream>>>(y, cf, out);
}

// Round 3
// 136.243 us; speedup vs baseline: 2.1770x; 1.2285x over previous
//
#include <hip/hip_runtime.h>

#define TWO_M 512
#define NCOL  64
#define SK    264            // bf16 elements per Yt row: 256 k + 8 pad (16B-aligned rows)
#define SW    65             // fp32 write-out tile stride (odd -> conflict-free)

typedef short short8 __attribute__((ext_vector_type(8)));
typedef float f32x4  __attribute__((ext_vector_type(4)));

static __device__ __forceinline__ unsigned short f2bf(float f) {
    unsigned int u = __builtin_bit_cast(unsigned int, f);
    return (unsigned short)((u + 0x7fffu + ((u >> 16) & 1u)) >> 16);   // RNE
}

// One block per batch: Gram(MFMA) + recurrence + apply + coalesced write-out.
// LDS overlay:
//   phase G:  Yt bf16[64][SK]   @0      (33792 B)   Gl f32[64*64] @33792 (16384 B)
//   phase W:  Tw f32[256][SW]   @0      (66560 B)
//   bd f32[128]                 @66560  (512 B)
__global__ __launch_bounds__(512, 4) void gs_fused(const float* __restrict__ y,
                                                   float* __restrict__ out)
{
    __shared__ __align__(16) unsigned char smem[67072];
    unsigned short* Yt   = (unsigned short*)smem;
    unsigned int*   Yt32 = (unsigned int*)smem;
    float*          Gl   = (float*)(smem + 33792);
    float*          Tw   = (float*)smem;
    float*          bd   = (float*)(smem + 66560);

    const int   batch = blockIdx.x;
    const float* Y    = y + (size_t)batch * (TWO_M * NCOL);
    const int   tid   = threadIdx.x;
    const int   wave  = tid >> 6;
    const int   lane  = tid & 63;

    f32x4 acc[2] = {f32x4{0,0,0,0}, f32x4{0,0,0,0}};
    const int arow = 16 * (wave >> 1) + (lane & 15);   // A-fragment G-row
    const int bc0  = 32 * (wave & 1) + (lane & 15);    // B-fragment G-col base
    const int koff = (lane >> 4) * 8;

    // ---- Gram: two k-chunks of 256 rows ----
    for (int kc = 0; kc < 2; ++kc) {
        if (kc) __syncthreads();              // prev MFMA done reading Yt
        const float4* src = (const float4*)(Y + (size_t)kc * 256 * NCOL);
#pragma unroll
        for (int it = 0; it < 4; ++it) {
            const int g  = it * 512 + tid;    // 0..2047
            const int kp = g >> 4;            // local k-pair 0..127
            const int cq = g & 15;            // float4 column
            const float4 va = src[kp * 32 + cq];
            const float4 vb = src[kp * 32 + 16 + cq];
            const unsigned int p0 = (unsigned int)f2bf(va.x) | ((unsigned int)f2bf(vb.x) << 16);
            const unsigned int p1 = (unsigned int)f2bf(va.y) | ((unsigned int)f2bf(vb.y) << 16);
            const unsigned int p2 = (unsigned int)f2bf(va.z) | ((unsigned int)f2bf(vb.z) << 16);
            const unsigned int p3 = (unsigned int)f2bf(va.w) | ((unsigned int)f2bf(vb.w) << 16);
            const int c0 = 4 * cq;
            Yt32[(c0 + 0) * (SK / 2) + kp] = p0;
            Yt32[(c0 + 1) * (SK / 2) + kp] = p1;
            Yt32[(c0 + 2) * (SK / 2) + kp] = p2;
            Yt32[(c0 + 3) * (SK / 2) + kp] = p3;
        }
        __syncthreads();
#pragma unroll
        for (int kb = 0; kb < 256; kb += 32) {
            const short8 afrag = *(const short8*)&Yt[arow * SK + kb + koff];
#pragma unroll
            for (int j = 0; j < 2; ++j) {
                const short8 bfrag = *(const short8*)&Yt[(bc0 + 16 * j) * SK + kb + koff];
                acc[j] = __builtin_amdgcn_mfma_f32_16x16x32_bf16(afrag, bfrag, acc[j], 0, 0, 0);
            }
        }
    }

    // ---- G slab write (disjoint per wave) ----
#pragma unroll
    for (int j = 0; j < 2; ++j)
#pragma unroll
        for (int reg = 0; reg < 4; ++reg) {
            const int gr = 16 * (wave >> 1) + (lane >> 4) * 4 + reg;
            const int gc = 32 * (wave & 1) + 16 * j + (lane & 15);
            Gl[gr * 64 + gc] = acc[j][reg];
        }
    __syncthreads();

    // ---- issue apply-row loads early (hide under recurrence); L3-resident re-read ----
    float4 row[16];
    const float4* rsrc = (const float4*)(Y + (size_t)tid * NCOL);
#pragma unroll
    for (int t = 0; t < 16; ++t) row[t] = rsrc[t];
    float* vf = (float*)row;

    // ---- scalar recurrence on wave 0 (verified R1/R2 code), results -> bd ----
    if (wave == 0) {
        const int l = lane;
        const float d     = Gl[l * 64 + l];
        const float invd  = 1.0f / d;
        const float invd0 = __shfl(invd, 0);
        float T  = Gl[l] * invd0;
        float r  = T;
        float Nq = __shfl(T, 0) * invd0;
        float bj = __shfl(r, 1);
        float bsave = 0.f;
        for (int j = 1; j < 64; ++j) {
            const float invdj = __shfl(invd, j);
            const float Tprev = T;
            T = (Gl[j * 64 + l] - bj * Tprev) * invdj;
            const float cj = (__shfl(Tprev, j) - bj * Nq) * invdj;
            Nq = (__shfl(T, j) - bj * cj) * invdj;
            r  = T - r * cj;
            if (l == j) bsave = bj;
            bj = __shfl(r, (j + 1) & 63);
        }
        bd[l]      = bsave;
        bd[64 + l] = invd;
    }
    __syncthreads();

    // ---- apply: fp32 row recurrence in registers ----
    {
        float q = 0.f;
#pragma unroll
        for (int i = 0; i < 64; ++i) {
            q = (vf[i] - bd[i] * q) * bd[64 + i];
            vf[i] = q;
        }
    }

    // ---- write-out: two 256-row chunks through LDS transpose ----
#pragma unroll
    for (int c = 0; c < 2; ++c) {
        __syncthreads();                      // Tw region free (Yt/Gl dead, prev copy done)
        if ((tid >> 8) == c) {
            const int r = tid & 255;
            float* dst = &Tw[r * SW];
#pragma unroll
            for (int i = 0; i < 64; ++i) dst[i] = vf[i];
        }
        __syncthreads();
        float4* gdst = (float4*)(out + (size_t)batch * (TWO_M * NCOL) + (size_t)c * 256 * NCOL);
#pragma unroll
        for (int t = 0; t < 8; ++t) {
            const int g   = t * 512 + tid;    // 0..4095 float4s
            const int r   = g >> 4;
            const int cq  = g & 15;
            const float* s = &Tw[r * SW + 4 * cq];
            gdst[g] = float4{s[0], s[1], s[2], s[3]};
        }
    }
}

extern "C" void kernel_launch(void* const* d_in, const int* in_sizes, int n_in,
                              void* d_out, int out_size, void* d_ws, size_t ws_size,
                              hipStream_t stream)
{
    const float* y = (const float*)d_in[0];
    float* out = (float*)d_out;
    const int B = in_sizes[0] / (TWO_M * NCOL);
    gs_fused<<<dim3(B), dim3(512), 0, stream>>>(y, out);
}